// Round 7
// baseline (700.657 us; speedup 1.0000x reference)
//
#include <hip/hip_runtime.h>
#include <hip/hip_cooperative_groups.h>
namespace cg = cooperative_groups;

// Problem constants (match reference)
static constexpr int NN   = 65536;   // total nodes
static constexpr int NPG  = 256;     // nodes per graph
static constexpr int NB   = 256;     // graphs (batch)
static constexpr int EMB  = 128;     // gcn emb dim
static constexpr int NOUT = 512;     // n_embd

static constexpr int NBIN = 256;     // partitions over dst>>8 (256 nodes each)
static constexpr int CAP  = 4608;    // bin capacity: mean 4096 edges, +8 sigma

// Head GEMM tiling
static constexpr int BT = 8;         // batches per task
static constexpr int KS = 16;        // K-splits over the i axis
static constexpr int IC = NPG / KS;  // 16 i-iterations per task

static constexpr int GRID = 256;     // 1 block/CU co-residency is always satisfiable
static constexpr int TPB  = 1024;

struct Params {
    const int* src; const int* dst; int E;
    const float* nodes; const float* W1; const float* b1;
    const float* W2; const float* b2; const float* W3; const float* b3;
    int* gbin; int* partE; unsigned short* srt; int* rs; float* dinv;
    float4* y1; float4* y2; float4* agg2; float* V; float* partO;
    float* out;
};

union SharedU {
    struct { int hist[NBIN]; int loff[NBIN]; int base[NBIN]; int scanbuf[NBIN];
             int stage[4096]; } part;                               // 20.5 KB
    struct { float red[2][4][NOUT]; } bv;                           // 16 KB
    struct { int hist[NPG]; int scanb[NPG]; int off_[NPG];
             unsigned short stageS[CAP]; } csr;                     // 12.2 KB
    struct { float4 a_s[BT * IC]; } outp;                           // 2 KB
};

// Quad-per-node CSR gather pass (g in [0, NN*4)); first=true fuses layer-1.
__device__ __forceinline__ void agg_pass(int g, const int* __restrict__ rs,
                                         const unsigned short* __restrict__ srt,
                                         const float* __restrict__ dinv,
                                         const float* __restrict__ W1,
                                         const float* __restrict__ b1,
                                         const float4* __restrict__ yin,
                                         float4* __restrict__ yout, bool first) {
    bool act = (g < NN * 4);
    int i = act ? (g >> 2) : 0;
    int sub = g & 3;
    float ax = 0.f, ay = 0.f, az = 0.f;
    if (act) {
        int rsd = rs[i];
        int start = rsd & 0xFFFFF, deg = rsd >> 20;
        const unsigned short* sp = srt + (size_t)(i >> 8) * CAP + start;
        for (int k = sub; k < deg; k += 4) {
            float4 v = yin[sp[k]];
            ax += v.x; ay += v.y; az += v.z;
        }
    }
    ax += __shfl_xor(ax, 1); ay += __shfl_xor(ay, 1); az += __shfl_xor(az, 1);
    ax += __shfl_xor(ax, 2); ay += __shfl_xor(ay, 2); az += __shfl_xor(az, 2);
    if (act && sub == 0) {
        float4 self = yin[i];
        float di = dinv[i];
        float a0 = (ax + self.x) * di, a1 = (ay + self.y) * di, a2 = (az + self.z) * di;
        if (first) {
            float h[3];
#pragma unroll
            for (int k = 0; k < 3; k++) {
                float t = a0 * W1[0*3+k] + a1 * W1[1*3+k] + a2 * W1[2*3+k] + b1[k];
                t = (t >= 0.f) ? t : 0.1f * t;
                h[k] = t * di;
            }
            yout[i] = make_float4(h[0], h[1], h[2], 0.f);
        } else {
            yout[i] = make_float4(a0, a1, a2, 0.f);
        }
    }
}

// ============================ fused cooperative ============================
__global__ __launch_bounds__(TPB)
void k_fused(Params p) {
    __shared__ SharedU sh;
    cg::grid_group grid = cg::this_grid();
    int tid = threadIdx.x;
    int bid = blockIdx.x;

    // ---------- P1a: radix-partition 4096 edges by dst>>8 ----------
    {
        int epb = (p.E + NBIN - 1) / NBIN;       // 4096 for E=1M
        int e0 = bid * epb;
        int e1 = min(e0 + epb, p.E);
        if (tid < NBIN) sh.part.hist[tid] = 0;
        __syncthreads();

        int pk[4], bn[4], rk[4];
        int n = 0;
        int e = e0 + tid * 4;
        if (e + 4 <= e1) {
            int4 s4 = *(const int4*)(p.src + e);
            int4 d4 = *(const int4*)(p.dst + e);
            int ss[4] = {s4.x, s4.y, s4.z, s4.w};
            int dd[4] = {d4.x, d4.y, d4.z, d4.w};
#pragma unroll
            for (int k = 0; k < 4; k++) {
                pk[k] = ss[k] | ((dd[k] & 255) << 16);
                bn[k] = dd[k] >> 8;
                rk[k] = atomicAdd(&sh.part.hist[bn[k]], 1);
            }
            n = 4;
        } else {
            for (int k = 0; k < 4 && e + k < e1; k++) {
                int s = p.src[e+k], d = p.dst[e+k];
                pk[n] = s | ((d & 255) << 16);
                bn[n] = d >> 8;
                rk[n] = atomicAdd(&sh.part.hist[bn[n]], 1);
                n++;
            }
        }
        __syncthreads();

        if (tid < NBIN) sh.part.scanbuf[tid] = sh.part.hist[tid];
        __syncthreads();
        for (int off = 1; off < NBIN; off <<= 1) {
            int v = 0;
            if (tid < NBIN && tid >= off) v = sh.part.scanbuf[tid - off];
            __syncthreads();
            if (tid < NBIN) sh.part.scanbuf[tid] += v;
            __syncthreads();
        }
        if (tid < NBIN) {
            sh.part.loff[tid] = sh.part.scanbuf[tid] - sh.part.hist[tid];
            sh.part.base[tid] = atomicAdd(&p.gbin[tid], sh.part.hist[tid]);
        }
        __syncthreads();

        for (int k = 0; k < n; k++) sh.part.stage[sh.part.loff[bn[k]] + rk[k]] = pk[k];
        __syncthreads();

        int bin = tid >> 2;
        int cnt = sh.part.hist[bin], bs = sh.part.base[bin], lo = sh.part.loff[bin];
        for (int t = tid & 3; t < cnt; t += 4) {
            int gp = bs + t;
            if (gp < CAP) p.partE[bin * CAP + gp] = sh.part.stage[lo + t];
        }
    }
    __syncthreads();   // LDS union re-use barrier

    // ---------- P1b: buildV row i=bid (c-loop split across thread halves) ----------
    {
        int i = bid;
        int j = tid & 511;
        int half = tid >> 9;
        const float* w3 = p.W3 + (size_t)i * EMB * NOUT + (size_t)half * 64 * NOUT + j;
        float a0 = 0.f, a1 = 0.f, a2 = 0.f, a3 = 0.f;
        for (int c = 0; c < 64; c++) {
            float v = w3[(size_t)c * NOUT];
            int cc = half * 64 + c;
            a0 += p.W2[0*EMB+cc] * v;
            a1 += p.W2[1*EMB+cc] * v;
            a2 += p.W2[2*EMB+cc] * v;
            a3 += p.b2[cc]       * v;
        }
        sh.bv.red[half][0][j] = a0;
        sh.bv.red[half][1][j] = a1;
        sh.bv.red[half][2][j] = a2;
        sh.bv.red[half][3][j] = a3;
        __syncthreads();
        if (tid < NOUT) {
            float* o = p.V + (size_t)i * 4 * NOUT + tid;
#pragma unroll
            for (int k = 0; k < 4; k++)
                o[k * NOUT] = sh.bv.red[0][k][tid] + sh.bv.red[1][k][tid];
        }
    }
    __threadfence();
    grid.sync();

    // ---------- P2: per-bin CSR (counting sort, two L2 passes) ----------
    {
        int bin = bid;
        if (tid < NPG) sh.csr.hist[tid] = 0;
        __syncthreads();
        int cnt = min(p.gbin[bin], CAP);
        const int* pp = p.partE + (size_t)bin * CAP;
        for (int e = tid; e < cnt; e += TPB)
            atomicAdd(&sh.csr.hist[(pp[e] >> 16) & 255], 1);
        __syncthreads();
        if (tid < NPG) sh.csr.scanb[tid] = sh.csr.hist[tid];
        __syncthreads();
        for (int off = 1; off < NPG; off <<= 1) {
            int v = 0;
            if (tid < NPG && tid >= off) v = sh.csr.scanb[tid - off];
            __syncthreads();
            if (tid < NPG) sh.csr.scanb[tid] += v;
            __syncthreads();
        }
        if (tid < NPG) {
            int start = sh.csr.scanb[tid] - sh.csr.hist[tid];
            sh.csr.off_[tid] = start;
            int node = bin * NPG + tid;
            float di = rsqrtf((float)(sh.csr.hist[tid] + 1));   // +1 self-loop
            p.dinv[node] = di;
            p.y1[node] = make_float4(p.nodes[3*node+0] * di, p.nodes[3*node+1] * di,
                                     p.nodes[3*node+2] * di, 0.f);
            p.rs[node] = start | (sh.csr.hist[tid] << 20);
        }
        __syncthreads();
        for (int e = tid; e < cnt; e += TPB) {
            int pkv = pp[e];
            int pos = atomicAdd(&sh.csr.off_[(pkv >> 16) & 255], 1);
            sh.csr.stageS[pos] = (unsigned short)(pkv & 0xFFFF);
        }
        __syncthreads();
        const unsigned int* so = (const unsigned int*)sh.csr.stageS;
        unsigned int* g = (unsigned int*)(p.srt + (size_t)bin * CAP);
        for (int t = tid; t < (cnt + 1) >> 1; t += TPB) g[t] = so[t];
    }
    __threadfence();
    grid.sync();

    // ---------- P3: gather round 1 (fused layer-1 linear + leakyReLU) ----------
    agg_pass(bid * TPB + tid, p.rs, p.srt, p.dinv, p.W1, p.b1, p.y1, p.y2, true);
    __threadfence();
    grid.sync();

    // ---------- P4: gather round 2 ----------
    agg_pass(bid * TPB + tid, p.rs, p.srt, p.dinv, p.W1, p.b1, p.y2, p.agg2, false);
    __threadfence();
    grid.sync();

    // ---------- P5: split-K head (512 tasks, 2 per block) ----------
    for (int task = bid; task < (NB / BT) * KS; task += GRID) {
        int bg = task & 31;            // batch group 0..31
        int ks = task >> 5;            // k-split 0..15
        int b0 = bg * BT;
        int i0 = ks * IC;
        if (tid < BT * IC) {
            int t = tid / IC, i = tid % IC;
            sh.outp.a_s[tid] = p.agg2[(size_t)(b0 + t) * NPG + i0 + i];
        }
        __syncthreads();
        int j  = tid & 511;
        int th = tid >> 9;             // 0/1: handles batches th*4 .. th*4+3
        float acc[4] = {0.f, 0.f, 0.f, 0.f};
        const float* vj = p.V + (size_t)i0 * 4 * NOUT + j;
        for (int i = 0; i < IC; i++) {
            float v0 = vj[(size_t)(i*4+0) * NOUT];
            float v1 = vj[(size_t)(i*4+1) * NOUT];
            float v2 = vj[(size_t)(i*4+2) * NOUT];
            float v3 = vj[(size_t)(i*4+3) * NOUT];
#pragma unroll
            for (int t = 0; t < 4; t++) {
                float4 a = sh.outp.a_s[(th*4 + t) * IC + i];
                acc[t] += a.x * v0 + a.y * v1 + a.z * v2 + v3;
            }
        }
#pragma unroll
        for (int t = 0; t < 4; t++)
            p.partO[((size_t)ks * NB + b0 + th*4 + t) * NOUT + j] = acc[t];
        __syncthreads();
    }
    __threadfence();
    grid.sync();

    // ---------- P6: reduce partials + b3 -> out ----------
    int g = bid * TPB + tid;
    if (g < NB * NOUT) {
        int j = g & (NOUT - 1);
        float acc = p.b3[j];
#pragma unroll
        for (int s = 0; s < KS; s++) acc += p.partO[(size_t)s * NB * NOUT + g];
        p.out[g] = acc;
    }
}

// ===================== fallback: proven R4 multi-kernel =====================
__global__ __launch_bounds__(1024)
void k_partV(const int* __restrict__ src, const int* __restrict__ dst, int E,
             int* __restrict__ gbin, int* __restrict__ part,
             const float* __restrict__ W2, const float* __restrict__ b2,
             const float* __restrict__ W3, float* __restrict__ V) {
    int tid = threadIdx.x;
    int bid = blockIdx.x;
    if (bid >= NBIN) {
        int i = (bid - NBIN) * 2 + (tid >> 9);
        int j = tid & 511;
        float acc0 = 0.f, acc1 = 0.f, acc2 = 0.f, acc3 = 0.f;
        const float* w3 = W3 + (size_t)i * EMB * NOUT + j;
        for (int c = 0; c < EMB; c++) {
            float v = w3[(size_t)c * NOUT];
            acc0 += W2[0*EMB+c] * v;
            acc1 += W2[1*EMB+c] * v;
            acc2 += W2[2*EMB+c] * v;
            acc3 += b2[c]       * v;
        }
        float* o = V + (size_t)i * 4 * NOUT + j;
        o[0*NOUT] = acc0; o[1*NOUT] = acc1; o[2*NOUT] = acc2; o[3*NOUT] = acc3;
        return;
    }
    __shared__ int hist[NBIN], loff[NBIN], base[NBIN], scanbuf[NBIN];
    __shared__ int stage[4096];
    int epb = (E + NBIN - 1) / NBIN;
    int e0 = bid * epb;
    int e1 = min(e0 + epb, E);
    if (tid < NBIN) hist[tid] = 0;
    __syncthreads();
    int pk[4], bn[4], rk[4];
    int n = 0;
    int e = e0 + tid * 4;
    if (e + 4 <= e1) {
        int4 s4 = *(const int4*)(src + e);
        int4 d4 = *(const int4*)(dst + e);
        int ss[4] = {s4.x, s4.y, s4.z, s4.w};
        int dd[4] = {d4.x, d4.y, d4.z, d4.w};
#pragma unroll
        for (int k = 0; k < 4; k++) {
            pk[k] = ss[k] | ((dd[k] & 255) << 16);
            bn[k] = dd[k] >> 8;
            rk[k] = atomicAdd(&hist[bn[k]], 1);
        }
        n = 4;
    } else {
        for (int k = 0; k < 4 && e + k < e1; k++) {
            int s = src[e+k], d = dst[e+k];
            pk[n] = s | ((d & 255) << 16);
            bn[n] = d >> 8;
            rk[n] = atomicAdd(&hist[bn[n]], 1);
            n++;
        }
    }
    __syncthreads();
    if (tid < NBIN) scanbuf[tid] = hist[tid];
    __syncthreads();
    for (int off = 1; off < NBIN; off <<= 1) {
        int v = 0;
        if (tid < NBIN && tid >= off) v = scanbuf[tid - off];
        __syncthreads();
        if (tid < NBIN) scanbuf[tid] += v;
        __syncthreads();
    }
    if (tid < NBIN) {
        loff[tid] = scanbuf[tid] - hist[tid];
        base[tid] = atomicAdd(&gbin[tid], hist[tid]);
    }
    __syncthreads();
    for (int k = 0; k < n; k++) stage[loff[bn[k]] + rk[k]] = pk[k];
    __syncthreads();
    int bin = tid >> 2;
    int cnt = hist[bin], bs = base[bin], lo = loff[bin];
    for (int t = tid & 3; t < cnt; t += 4) {
        int gp = bs + t;
        if (gp < CAP) part[bin * CAP + gp] = stage[lo + t];
    }
}

__global__ void k_csr(const int* __restrict__ gbin, const int* __restrict__ part,
                      const float* __restrict__ nodes,
                      float* __restrict__ dinv, float4* __restrict__ y1,
                      int* __restrict__ rs, unsigned short* __restrict__ srt) {
    __shared__ int pkst[CAP];
    __shared__ int hist[NPG], scanb[NPG], off_[NPG];
    __shared__ unsigned short stageS[CAP];
    int tid = threadIdx.x, bin = blockIdx.x;
    hist[tid] = 0;
    __syncthreads();
    int cnt = min(gbin[bin], CAP);
    const int* pp = part + (size_t)bin * CAP;
    for (int e = tid; e < cnt; e += 256) {
        int p = pp[e];
        pkst[e] = p;
        atomicAdd(&hist[(p >> 16) & 255], 1);
    }
    __syncthreads();
    scanb[tid] = hist[tid];
    __syncthreads();
    for (int off = 1; off < NPG; off <<= 1) {
        int v = (tid >= off) ? scanb[tid - off] : 0;
        __syncthreads();
        scanb[tid] += v;
        __syncthreads();
    }
    int start = scanb[tid] - hist[tid];
    off_[tid] = start;
    int node = bin * NPG + tid;
    float di = rsqrtf((float)(hist[tid] + 1));
    dinv[node] = di;
    y1[node] = make_float4(nodes[3*node+0] * di, nodes[3*node+1] * di,
                           nodes[3*node+2] * di, 0.f);
    rs[node] = start | (hist[tid] << 20);
    __syncthreads();
    for (int e = tid; e < cnt; e += 256) {
        int p = pkst[e];
        int pos = atomicAdd(&off_[(p >> 16) & 255], 1);
        stageS[pos] = (unsigned short)(p & 0xFFFF);
    }
    __syncthreads();
    const unsigned int* so = (const unsigned int*)stageS;
    unsigned int* g = (unsigned int*)(srt + (size_t)bin * CAP);
    for (int t = tid; t < (cnt + 1) >> 1; t += 256) g[t] = so[t];
}

__global__ void k_agg1(const int* __restrict__ rs, const unsigned short* __restrict__ srt,
                       const float* __restrict__ dinv, const float4* __restrict__ y1,
                       const float* __restrict__ W1, const float* __restrict__ b1,
                       float4* __restrict__ y2) {
    int g = blockIdx.x * 256 + threadIdx.x;
    agg_pass(g, rs, srt, dinv, W1, b1, y1, y2, true);
}

__global__ void k_agg2(const int* __restrict__ rs, const unsigned short* __restrict__ srt,
                       const float* __restrict__ dinv, const float4* __restrict__ y2,
                       float4* __restrict__ agg2) {
    int g = blockIdx.x * 256 + threadIdx.x;
    agg_pass(g, rs, srt, dinv, nullptr, nullptr, y2, agg2, false);
}

__global__ void k_out_part(const float4* __restrict__ agg2, const float* __restrict__ V,
                           float* __restrict__ part) {
    __shared__ float4 a_s[BT * IC];
    int tid = threadIdx.x;
    int j  = blockIdx.x * 256 + tid;
    int b0 = blockIdx.y * BT;
    int i0 = blockIdx.z * IC;
    for (int idx = tid; idx < BT * IC; idx += 256) {
        int t = idx / IC, i = idx % IC;
        a_s[idx] = agg2[(size_t)(b0 + t) * NPG + i0 + i];
    }
    __syncthreads();
    float acc[BT];
#pragma unroll
    for (int t = 0; t < BT; t++) acc[t] = 0.f;
    const float* vj = V + (size_t)i0 * 4 * NOUT + j;
    for (int i = 0; i < IC; i++) {
        float v0 = vj[(size_t)(i*4+0) * NOUT];
        float v1 = vj[(size_t)(i*4+1) * NOUT];
        float v2 = vj[(size_t)(i*4+2) * NOUT];
        float v3 = vj[(size_t)(i*4+3) * NOUT];
#pragma unroll
        for (int t = 0; t < BT; t++) {
            float4 a = a_s[t*IC + i];
            acc[t] += a.x * v0 + a.y * v1 + a.z * v2 + v3;
        }
    }
#pragma unroll
    for (int t = 0; t < BT; t++)
        part[((size_t)blockIdx.z * NB + b0 + t) * NOUT + j] = acc[t];
}

__global__ void k_reduce(const float* __restrict__ part, const float* __restrict__ b3,
                         float* __restrict__ out) {
    int idx = blockIdx.x * 256 + threadIdx.x;
    int j = idx & (NOUT - 1);
    float acc = b3[j];
#pragma unroll
    for (int s = 0; s < KS; s++) acc += part[(size_t)s * NB * NOUT + idx];
    out[idx] = acc;
}

extern "C" void kernel_launch(void* const* d_in, const int* in_sizes, int n_in,
                              void* d_out, int out_size, void* d_ws, size_t ws_size,
                              hipStream_t stream) {
    const float* nodes = (const float*)d_in[0];
    const int*   ei    = (const int*)  d_in[1];
    const float* W1    = (const float*)d_in[2];
    const float* b1    = (const float*)d_in[3];
    const float* W2    = (const float*)d_in[4];
    const float* b2    = (const float*)d_in[5];
    const float* W3    = (const float*)d_in[6];
    const float* b3    = (const float*)d_in[7];

    const int E = in_sizes[1] / 2;

    // Workspace layout (16B-aligned blocks)
    char* ws = (char*)d_ws;
    int*    gbin  = (int*)ws;                                 // 256 ints (pad 1 KB)
    float4* y1    = (float4*)(ws + 1024);                     // NN float4 (1 MB)
    float4* y2    = y1 + NN;                                  // 1 MB
    float4* agg2  = y2 + NN;                                  // 1 MB
    float*  V     = (float*)(agg2 + NN);                      // 2 MB
    float*  partO = V + (size_t)NPG * 4 * NOUT;               // 8 MB
    int*    partE = (int*)(partO + (size_t)KS * NB * NOUT);   // 4.7 MB
    unsigned short* srt = (unsigned short*)(partE + (size_t)NBIN * CAP); // 2.4 MB
    int*    rs    = (int*)(srt + (size_t)NBIN * CAP);         // 256 KB
    float*  dinv  = (float*)(rs + NN);                        // 256 KB

    Params p;
    p.src = ei; p.dst = ei + E; p.E = E;
    p.nodes = nodes; p.W1 = W1; p.b1 = b1; p.W2 = W2; p.b2 = b2; p.W3 = W3; p.b3 = b3;
    p.gbin = gbin; p.partE = partE; p.srt = srt; p.rs = rs; p.dinv = dinv;
    p.y1 = y1; p.y2 = y2; p.agg2 = agg2; p.V = V; p.partO = partO;
    p.out = (float*)d_out;

    hipMemsetAsync(gbin, 0, NBIN * 4, stream);

    void* args[] = { (void*)&p };
    hipError_t err = hipLaunchCooperativeKernel((void*)k_fused, dim3(GRID), dim3(TPB),
                                                args, 0, stream);
    if (err != hipSuccess) {
        (void)hipGetLastError();   // clear sticky error, use proven multi-kernel path
        k_partV   <<<NBIN + 128, 1024, 0, stream>>>(p.src, p.dst, E, gbin, partE,
                                                    W2, b2, W3, V);
        k_csr     <<<NBIN,  256, 0, stream>>>(gbin, partE, nodes, dinv, y1, rs, srt);
        k_agg1    <<<NN*4/256, 256, 0, stream>>>(rs, srt, dinv, y1, W1, b1, y2);
        k_agg2    <<<NN*4/256, 256, 0, stream>>>(rs, srt, dinv, y2, agg2);
        k_out_part<<<dim3(2, NB/BT, KS), 256, 0, stream>>>(agg2, V, partO);
        k_reduce  <<<NB*NOUT/256,        256, 0, stream>>>(partO, b3, p.out);
    }
}

// Round 8
// 168.184 us; speedup vs baseline: 4.1660x; 4.1660x over previous
//
#include <hip/hip_runtime.h>

// Problem constants (match reference)
static constexpr int NN   = 65536;   // total nodes
static constexpr int NPG  = 256;     // nodes per graph
static constexpr int NB   = 256;     // graphs (batch)
static constexpr int EMB  = 128;     // gcn emb dim
static constexpr int NOUT = 512;     // n_embd

static constexpr int NBIN = 256;     // partitions over dst>>8 (256 nodes each)
static constexpr int CAP  = 4608;    // bin capacity: mean 4096 edges, +8 sigma

// Head GEMM tiling
static constexpr int BT = 8;         // batches per block
static constexpr int KS = 16;        // K-splits over the i axis
static constexpr int IC = NPG / KS;  // 16 i-iterations per block

// Fused partition (blocks 0..255) + buildV (blocks 256..511; 1 V-row each).
// V4[i][j] = float4(sum_c W2[k][c]*W3[i*128+c][j] for k=0..2, b2-row in .w)
// packed edge = src | (dst&255)<<16
__global__ __launch_bounds__(1024)
void k_partV(const int* __restrict__ src, const int* __restrict__ dst, int E,
             int* __restrict__ gbin, int* __restrict__ part,
             const float* __restrict__ W2, const float* __restrict__ b2,
             const float* __restrict__ W3, float4* __restrict__ V4) {
    union SH {
        struct { int hist[NBIN]; int loff[NBIN]; int base[NBIN]; int scanbuf[NBIN];
                 int stage[4096]; } part;                           // 20.5 KB
        struct { float red[2][4][NOUT]; } bv;                       // 16 KB
    };
    __shared__ SH sh;
    int tid = threadIdx.x;
    int bid = blockIdx.x;

    if (bid >= NBIN) {
        // ---- buildV: one i-row, c-loop halved across thread groups ----
        int i = bid - NBIN;
        int j = tid & 511;
        int half = tid >> 9;
        const float* w3 = W3 + (size_t)i * EMB * NOUT + (size_t)half * 64 * NOUT + j;
        float a0 = 0.f, a1 = 0.f, a2 = 0.f, a3 = 0.f;
        for (int c = 0; c < 64; c++) {
            float v = w3[(size_t)c * NOUT];
            int cc = half * 64 + c;
            a0 += W2[0*EMB+cc] * v;
            a1 += W2[1*EMB+cc] * v;
            a2 += W2[2*EMB+cc] * v;
            a3 += b2[cc]       * v;
        }
        sh.bv.red[half][0][j] = a0;
        sh.bv.red[half][1][j] = a1;
        sh.bv.red[half][2][j] = a2;
        sh.bv.red[half][3][j] = a3;
        __syncthreads();
        if (tid < NOUT) {
            float4 r;
            r.x = sh.bv.red[0][0][tid] + sh.bv.red[1][0][tid];
            r.y = sh.bv.red[0][1][tid] + sh.bv.red[1][1][tid];
            r.z = sh.bv.red[0][2][tid] + sh.bv.red[1][2][tid];
            r.w = sh.bv.red[0][3][tid] + sh.bv.red[1][3][tid];
            V4[(size_t)i * NOUT + tid] = r;
        }
        return;
    }
    // ---- partition role ----
    int epb = (E + NBIN - 1) / NBIN;          // 4096 for E=1M
    int e0 = bid * epb;
    int e1 = min(e0 + epb, E);
    if (tid < NBIN) sh.part.hist[tid] = 0;
    __syncthreads();

    int pk[4], bn[4], rk[4];
    int n = 0;
    int e = e0 + tid * 4;
    if (e + 4 <= e1) {
        int4 s4 = *(const int4*)(src + e);
        int4 d4 = *(const int4*)(dst + e);
        int ss[4] = {s4.x, s4.y, s4.z, s4.w};
        int dd[4] = {d4.x, d4.y, d4.z, d4.w};
#pragma unroll
        for (int k = 0; k < 4; k++) {
            pk[k] = ss[k] | ((dd[k] & 255) << 16);
            bn[k] = dd[k] >> 8;
            rk[k] = atomicAdd(&sh.part.hist[bn[k]], 1);
        }
        n = 4;
    } else {
        for (int k = 0; k < 4 && e + k < e1; k++) {
            int s = src[e+k], d = dst[e+k];
            pk[n] = s | ((d & 255) << 16);
            bn[n] = d >> 8;
            rk[n] = atomicAdd(&sh.part.hist[bn[n]], 1);
            n++;
        }
    }
    __syncthreads();

    if (tid < NBIN) sh.part.scanbuf[tid] = sh.part.hist[tid];
    __syncthreads();
    for (int off = 1; off < NBIN; off <<= 1) {
        int v = 0;
        if (tid < NBIN && tid >= off) v = sh.part.scanbuf[tid - off];
        __syncthreads();
        if (tid < NBIN) sh.part.scanbuf[tid] += v;
        __syncthreads();
    }
    if (tid < NBIN) {
        sh.part.loff[tid] = sh.part.scanbuf[tid] - sh.part.hist[tid];
        sh.part.base[tid] = atomicAdd(&gbin[tid], sh.part.hist[tid]);
    }
    __syncthreads();

    for (int k = 0; k < n; k++) sh.part.stage[sh.part.loff[bn[k]] + rk[k]] = pk[k];
    __syncthreads();

    int bin = tid >> 2;
    int cnt = sh.part.hist[bin], bs = sh.part.base[bin], lo = sh.part.loff[bin];
    for (int t = tid & 3; t < cnt; t += 4) {
        int gp = bs + t;
        if (gp < CAP) part[bin * CAP + gp] = sh.part.stage[lo + t];
    }
}

// Per-bin CSR build (counting sort by dst) + degprep fused. 512 threads.
__global__ __launch_bounds__(512)
void k_csr(const int* __restrict__ gbin, const int* __restrict__ part,
           const float* __restrict__ nodes,
           float* __restrict__ dinv, float4* __restrict__ y1,
           int* __restrict__ rs, unsigned short* __restrict__ srt) {
    __shared__ int pkst[CAP];
    __shared__ int hist[NPG], scanb[NPG], off_[NPG];
    __shared__ unsigned short stageS[CAP];
    int tid = threadIdx.x, bin = blockIdx.x;
    if (tid < NPG) hist[tid] = 0;
    __syncthreads();
    int cnt = min(gbin[bin], CAP);
    const int* pp = part + (size_t)bin * CAP;
    for (int e = tid; e < cnt; e += 512) {
        int p = pp[e];
        pkst[e] = p;
        atomicAdd(&hist[(p >> 16) & 255], 1);
    }
    __syncthreads();
    if (tid < NPG) scanb[tid] = hist[tid];
    __syncthreads();
    for (int off = 1; off < NPG; off <<= 1) {
        int v = 0;
        if (tid < NPG && tid >= off) v = scanb[tid - off];
        __syncthreads();
        if (tid < NPG) scanb[tid] += v;
        __syncthreads();
    }
    if (tid < NPG) {
        int start = scanb[tid] - hist[tid];
        off_[tid] = start;
        int node = bin * NPG + tid;
        float di = rsqrtf((float)(hist[tid] + 1));   // +1 self-loop
        dinv[node] = di;
        y1[node] = make_float4(nodes[3*node+0] * di, nodes[3*node+1] * di,
                               nodes[3*node+2] * di, 0.f);
        rs[node] = start | (hist[tid] << 20);
    }
    __syncthreads();
    for (int e = tid; e < cnt; e += 512) {
        int p = pkst[e];
        int pos = atomicAdd(&off_[(p >> 16) & 255], 1);
        stageS[pos] = (unsigned short)(p & 0xFFFF);
    }
    __syncthreads();
    const unsigned int* so = (const unsigned int*)stageS;
    unsigned int* g = (unsigned int*)(srt + (size_t)bin * CAP);
    for (int t = tid; t < (cnt + 1) >> 1; t += 512) g[t] = so[t];
}

// Octet-per-node CSR gather (8 lanes/node; deg~16 -> 2 loads/lane).
__device__ __forceinline__ void agg_pass(int g, const int* __restrict__ rs,
                                         const unsigned short* __restrict__ srt,
                                         const float* __restrict__ dinv,
                                         const float* __restrict__ W1,
                                         const float* __restrict__ b1,
                                         const float4* __restrict__ yin,
                                         float4* __restrict__ yout, bool first) {
    int i = g >> 3, sub = g & 7;
    int rsd = rs[i];
    int start = rsd & 0xFFFFF, deg = rsd >> 20;
    const unsigned short* sp = srt + (size_t)(i >> 8) * CAP + start;
    float ax = 0.f, ay = 0.f, az = 0.f;
    for (int k = sub; k < deg; k += 8) {
        float4 v = yin[sp[k]];
        ax += v.x; ay += v.y; az += v.z;
    }
    ax += __shfl_xor(ax, 1); ay += __shfl_xor(ay, 1); az += __shfl_xor(az, 1);
    ax += __shfl_xor(ax, 2); ay += __shfl_xor(ay, 2); az += __shfl_xor(az, 2);
    ax += __shfl_xor(ax, 4); ay += __shfl_xor(ay, 4); az += __shfl_xor(az, 4);
    if (sub == 0) {
        float4 self = yin[i];
        float di = dinv[i];
        float a0 = (ax + self.x) * di, a1 = (ay + self.y) * di, a2 = (az + self.z) * di;
        if (first) {
            float h[3];
#pragma unroll
            for (int k = 0; k < 3; k++) {
                float t = a0 * W1[0*3+k] + a1 * W1[1*3+k] + a2 * W1[2*3+k] + b1[k];
                t = (t >= 0.f) ? t : 0.1f * t;
                h[k] = t * di;
            }
            yout[i] = make_float4(h[0], h[1], h[2], 0.f);
        } else {
            yout[i] = make_float4(a0, a1, a2, 0.f);
        }
    }
}

__global__ void k_agg1(const int* __restrict__ rs, const unsigned short* __restrict__ srt,
                       const float* __restrict__ dinv, const float4* __restrict__ y1,
                       const float* __restrict__ W1, const float* __restrict__ b1,
                       float4* __restrict__ y2) {
    agg_pass(blockIdx.x * 256 + threadIdx.x, rs, srt, dinv, W1, b1, y1, y2, true);
}

__global__ void k_agg2(const int* __restrict__ rs, const unsigned short* __restrict__ srt,
                       const float* __restrict__ dinv, const float4* __restrict__ y2,
                       float4* __restrict__ agg2) {
    agg_pass(blockIdx.x * 256 + threadIdx.x, rs, srt, dinv, nullptr, nullptr,
             y2, agg2, false);
}

// Split-K head: one float4 V-load per (i,j).
__global__ void k_out_part(const float4* __restrict__ agg2, const float4* __restrict__ V4,
                           float* __restrict__ part) {
    __shared__ float4 a_s[BT * IC];
    int tid = threadIdx.x;
    int j  = blockIdx.x * 256 + tid;
    int b0 = blockIdx.y * BT;
    int i0 = blockIdx.z * IC;
    for (int idx = tid; idx < BT * IC; idx += 256) {
        int t = idx / IC, i = idx % IC;
        a_s[idx] = agg2[(size_t)(b0 + t) * NPG + i0 + i];
    }
    __syncthreads();

    float acc[BT];
#pragma unroll
    for (int t = 0; t < BT; t++) acc[t] = 0.f;

    const float4* vj = V4 + (size_t)i0 * NOUT + j;
    for (int i = 0; i < IC; i++) {
        float4 v = vj[(size_t)i * NOUT];
#pragma unroll
        for (int t = 0; t < BT; t++) {
            float4 a = a_s[t*IC + i];
            acc[t] += a.x * v.x + a.y * v.y + a.z * v.z + v.w;
        }
    }
#pragma unroll
    for (int t = 0; t < BT; t++)
        part[((size_t)blockIdx.z * NB + b0 + t) * NOUT + j] = acc[t];
}

// out = b3 + sum_s part[s]  (float4-vectorized)
__global__ void k_reduce(const float4* __restrict__ part4, const float4* __restrict__ b3_4,
                         float4* __restrict__ out4) {
    int idx = blockIdx.x * 256 + threadIdx.x;     // over NB*NOUT/4 = 32768
    int j4 = idx & (NOUT/4 - 1);
    float4 acc = b3_4[j4];
#pragma unroll
    for (int s = 0; s < KS; s++) {
        float4 v = part4[(size_t)s * (NB*NOUT/4) + idx];
        acc.x += v.x; acc.y += v.y; acc.z += v.z; acc.w += v.w;
    }
    out4[idx] = acc;
}

extern "C" void kernel_launch(void* const* d_in, const int* in_sizes, int n_in,
                              void* d_out, int out_size, void* d_ws, size_t ws_size,
                              hipStream_t stream) {
    const float* nodes = (const float*)d_in[0];
    const int*   ei    = (const int*)  d_in[1];
    const float* W1    = (const float*)d_in[2];
    const float* b1    = (const float*)d_in[3];
    const float* W2    = (const float*)d_in[4];
    const float* b2    = (const float*)d_in[5];
    const float* W3    = (const float*)d_in[6];
    const float* b3    = (const float*)d_in[7];

    const int E = in_sizes[1] / 2;
    const int* src = ei;
    const int* dst = ei + E;

    // Workspace layout (16B-aligned blocks)
    char* ws = (char*)d_ws;
    int*    gbin  = (int*)ws;                                 // 256 ints (pad 1 KB)
    float4* y1    = (float4*)(ws + 1024);                     // NN float4 (1 MB)
    float4* y2    = y1 + NN;                                  // 1 MB
    float4* agg2  = y2 + NN;                                  // 1 MB
    float4* V4    = agg2 + NN;                                // NPG*NOUT float4 (2 MB)
    float*  partO = (float*)(V4 + (size_t)NPG * NOUT);        // KS*NB*NOUT (8 MB)
    int*    partE = (int*)(partO + (size_t)KS * NB * NOUT);   // NBIN*CAP ints (4.7 MB)
    unsigned short* srt = (unsigned short*)(partE + (size_t)NBIN * CAP); // 2.4 MB
    int*    rs    = (int*)(srt + (size_t)NBIN * CAP);         // 256 KB
    float*  dinv  = (float*)(rs + NN);                        // 256 KB

    hipMemsetAsync(gbin, 0, NBIN * 4, stream);
    k_partV   <<<2*NBIN, 1024, 0, stream>>>(src, dst, E, gbin, partE, W2, b2, W3, V4);
    k_csr     <<<NBIN,    512, 0, stream>>>(gbin, partE, nodes, dinv, y1, rs, srt);
    k_agg1    <<<NN*8/256, 256, 0, stream>>>(rs, srt, dinv, y1, W1, b1, y2);
    k_agg2    <<<NN*8/256, 256, 0, stream>>>(rs, srt, dinv, y2, agg2);
    k_out_part<<<dim3(2, NB/BT, KS), 256, 0, stream>>>(agg2, V4, partO);
    k_reduce  <<<NB*NOUT/4/256,      256, 0, stream>>>((const float4*)partO,
                                                       (const float4*)b3, (float4*)d_out);
}